// Round 1
// baseline (74.551 us; speedup 1.0000x reference)
//
#include <hip/hip_runtime.h>

// FastFood random features, D=64, fp32.
// One wave (64 lanes) processes 4 rows per iteration.
// Lane l holds elements e = 4*(l&15)..4*(l&15)+3 of row (l>>4).
// FWHT64 = 2 in-lane stages (element bits 0,1) + 4 __shfl_xor stages
// (masks 1,2,4,8 = element bits 2..5; masks < 16 keep the 16-lane row group).
// Permutation new[j] = old[P[j]]*G[j]: 4 shfls from lane (P[j]>>2) + select on P[j]&3.

__global__ __launch_bounds__(256) void fastfood_kernel(
    const float* __restrict__ x,
    const float* __restrict__ B,
    const float* __restrict__ G,
    const float* __restrict__ S,
    const int*   __restrict__ P,
    float* __restrict__ out,
    long long nq)  // number of 4-row quads
{
    const int l  = threadIdx.x & 63;
    const long long wid    = ((long long)blockIdx.x * blockDim.x + threadIdx.x) >> 6;
    const long long nwaves = ((long long)gridDim.x * blockDim.x) >> 6;

    const int e0 = (l & 15) << 2;        // first of this lane's 4 element slots
    const int gbase = l & 48;            // row-group bits of the lane id

    const float c1 = 0.35355339059327373f;  // 64^(-1/4) = sqrt(softmax_temp)
    const float c2 = 0.125f;                // sqrt(1/64)

    // Per-lane constants (hoisted out of the row loop; tiny arrays, L1-resident).
    const float bs0 = B[e0+0]*c1, bs1 = B[e0+1]*c1, bs2 = B[e0+2]*c1, bs3 = B[e0+3]*c1;
    const float gg0 = G[e0+0],    gg1 = G[e0+1],    gg2 = G[e0+2],    gg3 = G[e0+3];
    const float ss0 = S[e0+0]*c2, ss1 = S[e0+1]*c2, ss2 = S[e0+2]*c2, ss3 = S[e0+3]*c2;

    const int pj0 = P[e0+0], pj1 = P[e0+1], pj2 = P[e0+2], pj3 = P[e0+3];
    const int sl0 = gbase | (pj0 >> 2), sl1 = gbase | (pj1 >> 2),
              sl2 = gbase | (pj2 >> 2), sl3 = gbase | (pj3 >> 2);
    const bool b0_0 = pj0 & 1, b1_0 = pj0 & 2;
    const bool b0_1 = pj1 & 1, b1_1 = pj1 & 2;
    const bool b0_2 = pj2 & 1, b1_2 = pj2 & 2;
    const bool b0_3 = pj3 & 1, b1_3 = pj3 & 2;

    const float4* __restrict__ xin  = (const float4*)x;
    float4* __restrict__       yout = (float4*)out;

    for (long long q = wid; q < nq; q += nwaves) {
        const float4 v4 = xin[q * 64 + l];
        float v0 = v4.x * bs0, v1 = v4.y * bs1, v2 = v4.z * bs2, v3 = v4.w * bs3;

        // ---- FWHT #1 ----
        // in-lane: element bit 0 then bit 1
        {
            float t0 = v0 + v1, t1 = v0 - v1, t2 = v2 + v3, t3 = v2 - v3;
            v0 = t0 + t2; v2 = t0 - t2; v1 = t1 + t3; v3 = t1 - t3;
        }
        // cross-lane: element bits 2..5  (lane-pos bits 0..3)
        #define XSTAGE(m)                                                  \
        {                                                                  \
            float o0 = __shfl_xor(v0, m), o1 = __shfl_xor(v1, m);          \
            float o2 = __shfl_xor(v2, m), o3 = __shfl_xor(v3, m);          \
            const bool hi = (l & (m)) != 0;                                \
            v0 = hi ? o0 - v0 : v0 + o0;                                   \
            v1 = hi ? o1 - v1 : v1 + o1;                                   \
            v2 = hi ? o2 - v2 : v2 + o2;                                   \
            v3 = hi ? o3 - v3 : v3 + o3;                                   \
        }
        XSTAGE(1) XSTAGE(2) XSTAGE(4) XSTAGE(8)

        // ---- permutation gather + G ----
        float f0, f1, f2, f3;
        {
            float a0 = __shfl(v0, sl0), a1 = __shfl(v1, sl0),
                  a2 = __shfl(v2, sl0), a3 = __shfl(v3, sl0);
            f0 = (b1_0 ? (b0_0 ? a3 : a2) : (b0_0 ? a1 : a0)) * gg0;
        }
        {
            float a0 = __shfl(v0, sl1), a1 = __shfl(v1, sl1),
                  a2 = __shfl(v2, sl1), a3 = __shfl(v3, sl1);
            f1 = (b1_1 ? (b0_1 ? a3 : a2) : (b0_1 ? a1 : a0)) * gg1;
        }
        {
            float a0 = __shfl(v0, sl2), a1 = __shfl(v1, sl2),
                  a2 = __shfl(v2, sl2), a3 = __shfl(v3, sl2);
            f2 = (b1_2 ? (b0_2 ? a3 : a2) : (b0_2 ? a1 : a0)) * gg2;
        }
        {
            float a0 = __shfl(v0, sl3), a1 = __shfl(v1, sl3),
                  a2 = __shfl(v2, sl3), a3 = __shfl(v3, sl3);
            f3 = (b1_3 ? (b0_3 ? a3 : a2) : (b0_3 ? a1 : a0)) * gg3;
        }

        // ---- FWHT #2 ----
        {
            float t0 = f0 + f1, t1 = f0 - f1, t2 = f2 + f3, t3 = f2 - f3;
            f0 = t0 + t2; f2 = t0 - t2; f1 = t1 + t3; f3 = t1 - t3;
        }
        #define XSTAGEF(m)                                                 \
        {                                                                  \
            float o0 = __shfl_xor(f0, m), o1 = __shfl_xor(f1, m);          \
            float o2 = __shfl_xor(f2, m), o3 = __shfl_xor(f3, m);          \
            const bool hi = (l & (m)) != 0;                                \
            f0 = hi ? o0 - f0 : f0 + o0;                                   \
            f1 = hi ? o1 - f1 : f1 + o1;                                   \
            f2 = hi ? o2 - f2 : f2 + o2;                                   \
            f3 = hi ? o3 - f3 : f3 + o3;                                   \
        }
        XSTAGEF(1) XSTAGEF(2) XSTAGEF(4) XSTAGEF(8)

        float4 o;
        o.x = f0 * ss0; o.y = f1 * ss1; o.z = f2 * ss2; o.w = f3 * ss3;
        yout[q * 64 + l] = o;
    }
    #undef XSTAGE
    #undef XSTAGEF
}

extern "C" void kernel_launch(void* const* d_in, const int* in_sizes, int n_in,
                              void* d_out, int out_size, void* d_ws, size_t ws_size,
                              hipStream_t stream) {
    const float* x = (const float*)d_in[0];
    const float* B = (const float*)d_in[1];
    const float* G = (const float*)d_in[2];
    const float* S = (const float*)d_in[3];
    const int*   P = (const int*)d_in[4];
    float* out = (float*)d_out;

    const long long nq = (long long)in_sizes[0] / 256;  // 4 rows of 64 per quad

    const int block = 256;
    const int grid  = 2048;  // 8192 waves, grid-stride over 131072 quads
    fastfood_kernel<<<grid, block, 0, stream>>>(x, B, G, S, P, out, nq);
}

// Round 3
// 74.426 us; speedup vs baseline: 1.0017x; 1.0017x over previous
//
#include <hip/hip_runtime.h>

// FastFood random features, D=64, fp32.
// One wave (64 lanes) processes TWO independent 4-row quads per loop iteration
// (hand-interleaved chains a* and b* for ILP — the shfl chain is latency-bound).
// Lane l holds elements e = 4*(l&15)..4*(l&15)+3 of row (l>>4).
// FWHT64 = 2 in-lane stages (element bits 0,1) + 4 __shfl_xor stages
// (masks 1,2,4,8 = element bits 2..5; masks < 16 keep the 16-lane row group).
// Butterfly uses sign-xor trick: new = shfl_xor(v) + (v ^ signmask) — 2 VALU not 3.
// Permutation new[j] = old[P[j]]*G[j]: 4 shfls from lane (P[j]>>2) + select on P[j]&3.
// Output stored nontemporally to keep the input LLC-resident.

typedef float f32x4 __attribute__((ext_vector_type(4)));

__device__ __forceinline__ float fxs(float v, unsigned s) {
    return __uint_as_float(__float_as_uint(v) ^ s);
}

__global__ __launch_bounds__(256) void fastfood_kernel(
    const float* __restrict__ x,
    const float* __restrict__ B,
    const float* __restrict__ G,
    const float* __restrict__ S,
    const int*   __restrict__ P,
    float* __restrict__ out,
    long long nq)  // number of 4-row quads
{
    const int l = threadIdx.x & 63;
    const long long wid    = ((long long)blockIdx.x * blockDim.x + threadIdx.x) >> 6;
    const long long nwaves = ((long long)gridDim.x * blockDim.x) >> 6;

    const int e0 = (l & 15) << 2;        // first of this lane's 4 element slots
    const int gbase = l & 48;            // row-group bits of the lane id

    const float c1 = 0.35355339059327373f;  // 64^(-1/4)
    const float c2 = 0.125f;                // sqrt(1/64)

    // Per-lane constants (hoisted; tiny arrays, L1-resident).
    const float bs0 = B[e0+0]*c1, bs1 = B[e0+1]*c1, bs2 = B[e0+2]*c1, bs3 = B[e0+3]*c1;
    const float gg0 = G[e0+0],    gg1 = G[e0+1],    gg2 = G[e0+2],    gg3 = G[e0+3];
    const float ss0 = S[e0+0]*c2, ss1 = S[e0+1]*c2, ss2 = S[e0+2]*c2, ss3 = S[e0+3]*c2;

    const int pj0 = P[e0+0], pj1 = P[e0+1], pj2 = P[e0+2], pj3 = P[e0+3];
    const int sl0 = gbase | (pj0 >> 2), sl1 = gbase | (pj1 >> 2),
              sl2 = gbase | (pj2 >> 2), sl3 = gbase | (pj3 >> 2);
    const bool b0_0 = pj0 & 1, b1_0 = pj0 & 2;
    const bool b0_1 = pj1 & 1, b1_1 = pj1 & 2;
    const bool b0_2 = pj2 & 1, b1_2 = pj2 & 2;
    const bool b0_3 = pj3 & 1, b1_3 = pj3 & 2;

    // Butterfly sign masks per cross-lane stage (lane-pos bit set -> negate own value).
    const unsigned sg1 = (l & 1) ? 0x80000000u : 0u;
    const unsigned sg2 = (l & 2) ? 0x80000000u : 0u;
    const unsigned sg4 = (l & 4) ? 0x80000000u : 0u;
    const unsigned sg8 = (l & 8) ? 0x80000000u : 0u;

    const f32x4* __restrict__ xin  = (const f32x4*)x;
    f32x4* __restrict__       yout = (f32x4*)out;

    // In-lane radix-4 butterfly (element bits 0,1) on both chains.
    #define INL()                                                          \
    {                                                                      \
        float t0 = a0 + a1, t1 = a0 - a1, t2 = a2 + a3, t3 = a2 - a3;      \
        a0 = t0 + t2; a2 = t0 - t2; a1 = t1 + t3; a3 = t1 - t3;            \
        float u0 = b0 + b1, u1 = b0 - b1, u2 = b2 + b3, u3 = b2 - b3;      \
        b0 = u0 + u2; b2 = u0 - u2; b1 = u1 + u3; b3 = u1 - u3;            \
    }

    // Cross-lane butterfly stage on both chains.
    #define XST(m, sg)                                                     \
    {                                                                      \
        float oa0 = __shfl_xor(a0, m), oa1 = __shfl_xor(a1, m);            \
        float oa2 = __shfl_xor(a2, m), oa3 = __shfl_xor(a3, m);            \
        float ob0 = __shfl_xor(b0, m), ob1 = __shfl_xor(b1, m);            \
        float ob2 = __shfl_xor(b2, m), ob3 = __shfl_xor(b3, m);            \
        a0 = oa0 + fxs(a0, sg); a1 = oa1 + fxs(a1, sg);                    \
        a2 = oa2 + fxs(a2, sg); a3 = oa3 + fxs(a3, sg);                    \
        b0 = ob0 + fxs(b0, sg); b1 = ob1 + fxs(b1, sg);                    \
        b2 = ob2 + fxs(b2, sg); b3 = ob3 + fxs(b3, sg);                    \
    }

    for (long long q = wid; q < nq; q += 2 * nwaves) {
        const long long qa = q;
        const long long qb = q + nwaves;
        const bool hb = qb < nq;

        const f32x4 va = xin[qa * 64 + l];
        const f32x4 vb = xin[(hb ? qb : qa) * 64 + l];

        float a0 = va.x * bs0, a1 = va.y * bs1, a2 = va.z * bs2, a3 = va.w * bs3;
        float b0 = vb.x * bs0, b1 = vb.y * bs1, b2 = vb.z * bs2, b3 = vb.w * bs3;

        // ---- FWHT #1 ----
        INL()
        XST(1, sg1) XST(2, sg2) XST(4, sg4) XST(8, sg8)

        // ---- permutation gather + G ----
        float na0, na1, na2, na3, nb0, nb1, nb2, nb3;
        {
            float p0 = __shfl(a0, sl0), p1 = __shfl(a1, sl0),
                  p2 = __shfl(a2, sl0), p3 = __shfl(a3, sl0);
            float q0 = __shfl(b0, sl0), q1 = __shfl(b1, sl0),
                  q2 = __shfl(b2, sl0), q3 = __shfl(b3, sl0);
            na0 = (b1_0 ? (b0_0 ? p3 : p2) : (b0_0 ? p1 : p0)) * gg0;
            nb0 = (b1_0 ? (b0_0 ? q3 : q2) : (b0_0 ? q1 : q0)) * gg0;
        }
        {
            float p0 = __shfl(a0, sl1), p1 = __shfl(a1, sl1),
                  p2 = __shfl(a2, sl1), p3 = __shfl(a3, sl1);
            float q0 = __shfl(b0, sl1), q1 = __shfl(b1, sl1),
                  q2 = __shfl(b2, sl1), q3 = __shfl(b3, sl1);
            na1 = (b1_1 ? (b0_1 ? p3 : p2) : (b0_1 ? p1 : p0)) * gg1;
            nb1 = (b1_1 ? (b0_1 ? q3 : q2) : (b0_1 ? q1 : q0)) * gg1;
        }
        {
            float p0 = __shfl(a0, sl2), p1 = __shfl(a1, sl2),
                  p2 = __shfl(a2, sl2), p3 = __shfl(a3, sl2);
            float q0 = __shfl(b0, sl2), q1 = __shfl(b1, sl2),
                  q2 = __shfl(b2, sl2), q3 = __shfl(b3, sl2);
            na2 = (b1_2 ? (b0_2 ? p3 : p2) : (b0_2 ? p1 : p0)) * gg2;
            nb2 = (b1_2 ? (b0_2 ? q3 : q2) : (b0_2 ? q1 : q0)) * gg2;
        }
        {
            float p0 = __shfl(a0, sl3), p1 = __shfl(a1, sl3),
                  p2 = __shfl(a2, sl3), p3 = __shfl(a3, sl3);
            float q0 = __shfl(b0, sl3), q1 = __shfl(b1, sl3),
                  q2 = __shfl(b2, sl3), q3 = __shfl(b3, sl3);
            na3 = (b1_3 ? (b0_3 ? p3 : p2) : (b0_3 ? p1 : p0)) * gg3;
            nb3 = (b1_3 ? (b0_3 ? q3 : q2) : (b0_3 ? q1 : q0)) * gg3;
        }
        a0 = na0; a1 = na1; a2 = na2; a3 = na3;
        b0 = nb0; b1 = nb1; b2 = nb2; b3 = nb3;

        // ---- FWHT #2 ----
        INL()
        XST(1, sg1) XST(2, sg2) XST(4, sg4) XST(8, sg8)

        f32x4 oa, ob;
        oa.x = a0 * ss0; oa.y = a1 * ss1; oa.z = a2 * ss2; oa.w = a3 * ss3;
        ob.x = b0 * ss0; ob.y = b1 * ss1; ob.z = b2 * ss2; ob.w = b3 * ss3;
        __builtin_nontemporal_store(oa, &yout[qa * 64 + l]);
        if (hb) __builtin_nontemporal_store(ob, &yout[qb * 64 + l]);
    }
    #undef INL
    #undef XST
}

extern "C" void kernel_launch(void* const* d_in, const int* in_sizes, int n_in,
                              void* d_out, int out_size, void* d_ws, size_t ws_size,
                              hipStream_t stream) {
    const float* x = (const float*)d_in[0];
    const float* B = (const float*)d_in[1];
    const float* G = (const float*)d_in[2];
    const float* S = (const float*)d_in[3];
    const int*   P = (const int*)d_in[4];
    float* out = (float*)d_out;

    const long long nq = (long long)in_sizes[0] / 256;  // 4 rows of 64 per quad

    const int block = 256;
    const int grid  = 2048;  // 8192 waves; 16 quads/wave = 8 unrolled pairs
    fastfood_kernel<<<grid, block, 0, stream>>>(x, B, G, S, P, out, nq);
}

// Round 4
// 60.793 us; speedup vs baseline: 1.2263x; 1.2243x over previous
//
#include <hip/hip_runtime.h>

// FastFood random features, D=64, fp32 — LDS-transpose formulation.
//
// Previous (shfl-based) kernel was LDS-pipe-bound: 12 ds_bpermute per row
// ~= 59us of DS serialization. This version does both FWHT64s fully in-lane
// (lane owns an entire row in 64 VGPRs) and uses LDS only for layout
// transposes + the permutation gather: ~1.9 DS-instr/row => DS ~24us < HBM 42us.
//
// Per wave: one 64x64 tile (64 rows). Two layouts:
//   Q (coalesced): instr c, lane l  <->  row r=4c+(l>>4), cols e0..e0+3 (e0=(l&15)*4)
//                  -> elementwise B/G/S muls use 4 per-lane registers.
//   R (row-in-lane): lane l owns row l fully -> FWHT in registers, no shfl.
// LDS tile: 64 rows x 64 floats, XOR-swizzled:
//   fidx(row, col) = row*64 + (col ^ ((row&15)<<2))
// (xor touches only col bits 2..5 -> 16B alignment preserved; all b128
//  patterns land 8 lanes per 4-bank group = conflict-free floor).
//
// Phase order per tile (fences = s_waitcnt lgkmcnt(0) + compiler barrier;
// needed because cross-lane LDS dataflow is invisible to alias analysis):
//   load 16 chunks -> *B*c1 -> W1(Q) | R1(R) -> FWHT1 -> W2(R) |
//   R2 permuted gather + *G -> W3(Q, streamed) | R3(R) -> FWHT2 -> W4(R) |
//   R4(Q) -> *S*c2 -> nontemporal store.
// Hazards: W3(c) writes rows 4c..4c+3 only after R2(c) read them (program
// order, DS pipe in-order per wave); later chunks read strictly later rows.

typedef float f32x4 __attribute__((ext_vector_type(4)));

#define FENCE() asm volatile("s_waitcnt lgkmcnt(0)" ::: "memory")

#define FSTAGE(H)                                                   \
    _Pragma("unroll")                                               \
    for (int i = 0; i < 64; i += 2*(H)) {                           \
        _Pragma("unroll")                                           \
        for (int j = 0; j < (H); ++j) {                             \
            const float a = y[i+j], b = y[i+j+(H)];                 \
            y[i+j] = a + b; y[i+j+(H)] = a - b;                     \
        }                                                           \
    }

__global__ __launch_bounds__(128) void fastfood_kernel(
    const float* __restrict__ x,
    const float* __restrict__ Bv,
    const float* __restrict__ Gv,
    const float* __restrict__ Sv,
    const int*   __restrict__ Pv,
    float* __restrict__ out,
    int ntiles)
{
    __shared__ float lds_all[2 * 64 * 64];   // 32 KB: one 16 KB tile per wave
    const int l  = threadIdx.x & 63;
    const int wv = threadIdx.x >> 6;
    float* lds = &lds_all[wv * 4096];

    const int wid    = blockIdx.x * 2 + wv;
    const int nwaves = gridDim.x * 2;

    const int hi = l >> 4;      // 0..3
    const int lo = l & 15;      // 0..15
    const int e0 = lo << 2;     // this lane's 4 cols in Q layout

    const float c1 = 0.35355339059327373f;  // 64^(-1/4)
    const float c2 = 0.125f;                // sqrt(1/64)

    // Per-lane constants (Q-layout cols e0..e0+3).
    const float bs0 = Bv[e0+0]*c1, bs1 = Bv[e0+1]*c1, bs2 = Bv[e0+2]*c1, bs3 = Bv[e0+3]*c1;
    const float gg0 = Gv[e0+0],    gg1 = Gv[e0+1],    gg2 = Gv[e0+2],    gg3 = Gv[e0+3];
    const float ss0 = Sv[e0+0]*c2, ss1 = Sv[e0+1]*c2, ss2 = Sv[e0+2]*c2, ss3 = Sv[e0+3]*c2;
    const int   p0  = Pv[e0+0],    p1  = Pv[e0+1],    p2  = Pv[e0+2],    p3  = Pv[e0+3];

    const f32x4* __restrict__ xin  = (const f32x4*)x;
    f32x4* __restrict__       yout = (f32x4*)out;

    for (int t = wid; t < ntiles; t += nwaves) {
        const long long tb = (long long)t * 1024;   // tile base in f32x4 units

        // ---- load 16 coalesced chunks (issued back-to-back for MLP) ----
        f32x4 st[16];
        #pragma unroll
        for (int c = 0; c < 16; ++c) st[c] = xin[tb + c*64 + l];

        // ---- W1: *B*c1, write Q layout ----
        #pragma unroll
        for (int c = 0; c < 16; ++c) {
            const int r = 4*c + hi;
            f32x4 v = st[c];
            v.x *= bs0; v.y *= bs1; v.z *= bs2; v.w *= bs3;
            *(f32x4*)&lds[r*64 + (e0 ^ ((r & 15) << 2))] = v;
        }
        FENCE();

        // ---- R1: transposed read, lane owns row l ----
        float y[64];
        const int swl = lo << 2;   // swizzle for row l: (l&15)<<2
        #pragma unroll
        for (int k = 0; k < 16; ++k) {
            const f32x4 v = *(const f32x4*)&lds[l*64 + ((k << 2) ^ swl)];
            y[4*k+0] = v.x; y[4*k+1] = v.y; y[4*k+2] = v.z; y[4*k+3] = v.w;
        }

        // ---- FWHT #1, fully in-lane ----
        FSTAGE(1) FSTAGE(2) FSTAGE(4) FSTAGE(8) FSTAGE(16) FSTAGE(32)

        // ---- W2: write y1 back (R layout, row l) ----
        #pragma unroll
        for (int k = 0; k < 16; ++k) {
            f32x4 v;
            v.x = y[4*k+0]; v.y = y[4*k+1]; v.z = y[4*k+2]; v.w = y[4*k+3];
            *(f32x4*)&lds[l*64 + ((k << 2) ^ swl)] = v;
        }
        FENCE();

        // ---- R2: permuted gather + *G, W3: write y2 (Q layout, streamed) ----
        // reads of rows 4c..4c+3 precede the write to those rows (program order);
        // chunks c' > c touch strictly higher rows -> no hazard.
        #pragma unroll
        for (int c = 0; c < 16; ++c) {
            const int r  = 4*c + hi;
            const int rb = r * 64;
            const int sw = (r & 15) << 2;
            const float a0 = lds[rb + (p0 ^ sw)];
            const float a1 = lds[rb + (p1 ^ sw)];
            const float a2 = lds[rb + (p2 ^ sw)];
            const float a3 = lds[rb + (p3 ^ sw)];
            f32x4 v;
            v.x = a0 * gg0; v.y = a1 * gg1; v.z = a2 * gg2; v.w = a3 * gg3;
            *(f32x4*)&lds[rb + (e0 ^ sw)] = v;
        }
        FENCE();

        // ---- R3: read y2 row l ----
        #pragma unroll
        for (int k = 0; k < 16; ++k) {
            const f32x4 v = *(const f32x4*)&lds[l*64 + ((k << 2) ^ swl)];
            y[4*k+0] = v.x; y[4*k+1] = v.y; y[4*k+2] = v.z; y[4*k+3] = v.w;
        }

        // ---- FWHT #2 ----
        FSTAGE(1) FSTAGE(2) FSTAGE(4) FSTAGE(8) FSTAGE(16) FSTAGE(32)

        // ---- W4: write back (R layout) ----
        #pragma unroll
        for (int k = 0; k < 16; ++k) {
            f32x4 v;
            v.x = y[4*k+0]; v.y = y[4*k+1]; v.z = y[4*k+2]; v.w = y[4*k+3];
            *(f32x4*)&lds[l*64 + ((k << 2) ^ swl)] = v;
        }
        FENCE();

        // ---- R4: Q read, *S*c2, nontemporal store ----
        #pragma unroll
        for (int c = 0; c < 16; ++c) {
            const int r = 4*c + hi;
            f32x4 v = *(const f32x4*)&lds[r*64 + (e0 ^ ((r & 15) << 2))];
            v.x *= ss0; v.y *= ss1; v.z *= ss2; v.w *= ss3;
            __builtin_nontemporal_store(v, &yout[tb + c*64 + l]);
        }
        FENCE();   // R4 reads must complete before next iter's W1 overwrites
    }
}

extern "C" void kernel_launch(void* const* d_in, const int* in_sizes, int n_in,
                              void* d_out, int out_size, void* d_ws, size_t ws_size,
                              hipStream_t stream) {
    const float* x = (const float*)d_in[0];
    const float* B = (const float*)d_in[1];
    const float* G = (const float*)d_in[2];
    const float* S = (const float*)d_in[3];
    const int*   P = (const int*)d_in[4];
    float* out = (float*)d_out;

    const int ntiles = in_sizes[0] / 4096;   // 64 rows x 64 floats per tile

    const int block = 128;   // 2 waves, 32 KB LDS -> 5 blocks/CU, 10 waves/CU
    const int grid  = 1280;  // 5 per CU x 256 CUs; grid-stride over 8192 tiles
    fastfood_kernel<<<grid, block, 0, stream>>>(x, B, G, S, P, out, ntiles);
}

// Round 5
// 52.952 us; speedup vs baseline: 1.4079x; 1.1481x over previous
//
#include <hip/hip_runtime.h>

// FastFood random features, D=64, fp32 — LDS-transpose formulation, fence-free.
//
// R4 post-mortem: phase fences (lgkmcnt(0) drains) serialized each wave; with
// ~2.5 waves/SIMD there was no TLP to hide them -> latency-bound at 60us.
// This version relies on same-wave DS program-order (tile is wave-private;
// no cross-wave sharing) so NO explicit fences/barriers are needed: the
// compiler keeps LDS op order (can't prove runtime-indexed disjointness) and
// inserts counted lgkmcnt for register deps -> ds_reads overlap FWHT VALU.
// Next tile's global loads are prefetched after R2 so W1 never waits on HBM.
//
// Layouts per 64x64 tile (16 KB LDS per wave):
//   Q (coalesced): chunk c, lane l <-> row r=4c+(l>>4), cols e0..e0+3 (e0=(l&15)*4)
//   R (row-in-lane): lane l owns row l fully -> FWHT64 is pure in-lane VALU.
// LDS swizzle: fidx(row,col) = row*64 + (col ^ ((row&15)<<2))  (16B-preserving,
// all b128 patterns conflict-free; R2 b32 gathers are quarter-wave broadcasts).
//
// Phases: W1(Q,*B*c1) R1(R) FWHT1 R2(gather P,*G; write Q) [prefetch t+1]
//         R3(R) FWHT2 W4(R) R4(Q,*S*c2, nontemporal store).

typedef float f32x4 __attribute__((ext_vector_type(4)));

#define FSTAGE(H)                                                   \
    _Pragma("unroll")                                               \
    for (int i = 0; i < 64; i += 2*(H)) {                           \
        _Pragma("unroll")                                           \
        for (int j = 0; j < (H); ++j) {                             \
            const float a = y[i+j], b = y[i+j+(H)];                 \
            y[i+j] = a + b; y[i+j+(H)] = a - b;                     \
        }                                                           \
    }

__global__ __launch_bounds__(128) void fastfood_kernel(
    const float* __restrict__ x,
    const float* __restrict__ Bv,
    const float* __restrict__ Gv,
    const float* __restrict__ Sv,
    const int*   __restrict__ Pv,
    float* __restrict__ out,
    int ntiles)
{
    __shared__ float lds_all[2 * 64 * 64];   // 32 KB: one 16 KB tile per wave
    const int l  = threadIdx.x & 63;
    const int wv = threadIdx.x >> 6;
    float* lds = &lds_all[wv * 4096];

    const int wid    = blockIdx.x * 2 + wv;
    const int nwaves = gridDim.x * 2;

    const int hi = l >> 4;      // 0..3
    const int lo = l & 15;      // 0..15
    const int e0 = lo << 2;     // this lane's 4 cols in Q layout
    const int swl = lo << 2;    // R-layout swizzle for row l

    const float c1 = 0.35355339059327373f;  // 64^(-1/4)
    const float c2 = 0.125f;                // sqrt(1/64)

    const float bs0 = Bv[e0+0]*c1, bs1 = Bv[e0+1]*c1, bs2 = Bv[e0+2]*c1, bs3 = Bv[e0+3]*c1;
    const float gg0 = Gv[e0+0],    gg1 = Gv[e0+1],    gg2 = Gv[e0+2],    gg3 = Gv[e0+3];
    const float ss0 = Sv[e0+0]*c2, ss1 = Sv[e0+1]*c2, ss2 = Sv[e0+2]*c2, ss3 = Sv[e0+3]*c2;
    const int   p0  = Pv[e0+0],    p1  = Pv[e0+1],    p2  = Pv[e0+2],    p3  = Pv[e0+3];

    const f32x4* __restrict__ xin  = (const f32x4*)x;
    f32x4* __restrict__       yout = (f32x4*)out;

    int t = wid;
    if (t >= ntiles) return;

    // Prologue: load first tile.
    f32x4 st[16];
    {
        const long long tb = (long long)t * 1024;
        #pragma unroll
        for (int c = 0; c < 16; ++c) st[c] = xin[tb + c*64 + l];
    }

    for (; t < ntiles; t += nwaves) {
        const long long tb = (long long)t * 1024;

        // ---- W1: *B*c1, write Q layout ----
        #pragma unroll
        for (int c = 0; c < 16; ++c) {
            const int r = 4*c + hi;
            f32x4 v = st[c];
            v.x *= bs0; v.y *= bs1; v.z *= bs2; v.w *= bs3;
            *(f32x4*)&lds[r*64 + (e0 ^ ((r & 15) << 2))] = v;
        }

        // ---- R1: lane l reads its full row ----
        float y[64];
        #pragma unroll
        for (int k = 0; k < 16; ++k) {
            const f32x4 v = *(const f32x4*)&lds[l*64 + ((k << 2) ^ swl)];
            y[4*k+0] = v.x; y[4*k+1] = v.y; y[4*k+2] = v.z; y[4*k+3] = v.w;
        }

        // ---- FWHT #1, in-lane ----
        FSTAGE(1) FSTAGE(2) FSTAGE(4) FSTAGE(8) FSTAGE(16) FSTAGE(32)

        // ---- W2: write y1 back (R layout) ----
        #pragma unroll
        for (int k = 0; k < 16; ++k) {
            f32x4 v;
            v.x = y[4*k+0]; v.y = y[4*k+1]; v.z = y[4*k+2]; v.w = y[4*k+3];
            *(f32x4*)&lds[l*64 + ((k << 2) ^ swl)] = v;
        }

        // ---- R2: permuted gather + *G, write y2 (Q layout) ----
        // reads of rows 4c..4c+3 precede the write to those rows (same-wave
        // DS program order); chunks c' > c touch strictly higher rows.
        #pragma unroll
        for (int c = 0; c < 16; ++c) {
            const int r  = 4*c + hi;
            const int rb = r * 64;
            const int sw = (r & 15) << 2;
            const float a0 = lds[rb + (p0 ^ sw)];
            const float a1 = lds[rb + (p1 ^ sw)];
            const float a2 = lds[rb + (p2 ^ sw)];
            const float a3 = lds[rb + (p3 ^ sw)];
            f32x4 v;
            v.x = a0 * gg0; v.y = a1 * gg1; v.z = a2 * gg2; v.w = a3 * gg3;
            *(f32x4*)&lds[rb + (e0 ^ sw)] = v;
        }

        // ---- prefetch next tile (in flight across R3 + FWHT2 + W4) ----
        {
            const long long tn = (t + nwaves < ntiles) ? (long long)(t + nwaves)
                                                       : (long long)t;
            const long long nb = tn * 1024;
            #pragma unroll
            for (int c = 0; c < 16; ++c) st[c] = xin[nb + c*64 + l];
        }

        // ---- R3: read y2 row l ----
        #pragma unroll
        for (int k = 0; k < 16; ++k) {
            const f32x4 v = *(const f32x4*)&lds[l*64 + ((k << 2) ^ swl)];
            y[4*k+0] = v.x; y[4*k+1] = v.y; y[4*k+2] = v.z; y[4*k+3] = v.w;
        }

        // ---- FWHT #2 ----
        FSTAGE(1) FSTAGE(2) FSTAGE(4) FSTAGE(8) FSTAGE(16) FSTAGE(32)

        // ---- W4: write back (R layout) ----
        #pragma unroll
        for (int k = 0; k < 16; ++k) {
            f32x4 v;
            v.x = y[4*k+0]; v.y = y[4*k+1]; v.z = y[4*k+2]; v.w = y[4*k+3];
            *(f32x4*)&lds[l*64 + ((k << 2) ^ swl)] = v;
        }

        // ---- R4: Q read, *S*c2, nontemporal store ----
        // Next iteration's W1 writes issue after these reads (DS in-order).
        #pragma unroll
        for (int c = 0; c < 16; ++c) {
            const int r = 4*c + hi;
            f32x4 v = *(const f32x4*)&lds[r*64 + (e0 ^ ((r & 15) << 2))];
            v.x *= ss0; v.y *= ss1; v.z *= ss2; v.w *= ss3;
            __builtin_nontemporal_store(v, &yout[tb + c*64 + l]);
        }
    }
}

extern "C" void kernel_launch(void* const* d_in, const int* in_sizes, int n_in,
                              void* d_out, int out_size, void* d_ws, size_t ws_size,
                              hipStream_t stream) {
    const float* x = (const float*)d_in[0];
    const float* B = (const float*)d_in[1];
    const float* G = (const float*)d_in[2];
    const float* S = (const float*)d_in[3];
    const int*   P = (const int*)d_in[4];
    float* out = (float*)d_out;

    const int ntiles = in_sizes[0] / 4096;   // 64 rows x 64 floats per tile

    const int block = 128;   // 2 waves, 32 KB LDS -> 5 blocks/CU, 10 waves/CU
    const int grid  = 1280;  // LDS-capped full residency; grid-stride over tiles
    fastfood_kernel<<<grid, block, 0, stream>>>(x, B, G, S, P, out, ntiles);
}